// Round 3
// baseline (273.262 us; speedup 1.0000x reference)
//
#include <hip/hip_runtime.h>

// ROIAlign (tf.image.crop_and_resize, bilinear, extrapolation_value=0)
// features: [B=4, H=256, W=256, C=64] f32
// rois:     [B=4, N=64, 4] f32  (x1,y1,x2,y2) in image coords (/1024 normalized)
// out:      [B=4, N=64, 56, 56, C=64] f32
//
// R3: drop non-temporal stores (single-lever A/B vs R2).
//  Theory: the NT write path may cap the 205 MB output stream well below
//  the ~6.5 TB/s a cached write stream achieves (fillBufferAligned's own
//  rate). The original NT rationale ("keep features L2-resident") doesn't
//  hold: features are 67 MB vs 32 MB aggregate L2, and feature-line reuse
//  is within-block (µs reuse distance), so streaming cached writes can't
//  meaningfully evict live lines. Plain stores also let dirty L2 lines
//  drain after the kernel's end timestamp.
//
//  Everything else identical to R2:
//  - 16 lanes per position (4 channels each, float4); each thread computes
//    FOUR output rows (i0..i0+3) at one j -> roi fetch, j/t decode and the
//    whole x-pipeline shared across 4 rows.
//  - 16 independent 16B loads issued upfront (max MLP).
//  - roi load forced scalar via readfirstlane (rIdx wave-uniform).

#define CROP 56
#define FH 256
#define FW 256
#define FC 64

typedef float f32x4 __attribute__((ext_vector_type(4)));

__device__ __forceinline__ f32x4 lerp2d(f32x4 v00, f32x4 v01, f32x4 v10, f32x4 v11,
                                        float lx, float ly) {
    f32x4 top = v00 + (v01 - v00) * lx;
    f32x4 bot = v10 + (v11 - v10) * lx;
    return top + (bot - top) * ly;
}

__global__ __launch_bounds__(256) void roialign_kernel(
    const float* __restrict__ feats,
    const float* __restrict__ rois,
    float* __restrict__ out)
{
    const int g = blockIdx.x * 256 + threadIdx.x;

    const int c = (g & 15) << 2;          // channel offset (float4 chunk)
    const int p = g >> 4;                 // position-group index (j, 4-row group)
    const int j  = p % CROP;
    const int t  = p / CROP;
    const int ih = t % (CROP / 4);        // 0..13
    const int rIdx0 = t / (CROP / 4);     // b*64 + n
    const int i0 = ih * 4;

    // rIdx is wave-uniform (784 positions per roi, 4 positions per wave).
    const int rIdx = __builtin_amdgcn_readfirstlane(rIdx0);
    const int b = rIdx >> 6;

    const f32x4 roi = *reinterpret_cast<const f32x4*>(rois + rIdx * 4);
    const float inv_img = 1.0f / 1024.0f;
    const float x1 = roi.x * inv_img;
    const float y1 = roi.y * inv_img;
    const float x2 = roi.z * inv_img;
    const float y2 = roi.w * inv_img;

    const float hm1 = (float)(FH - 1);            // 255
    const float wm1 = (float)(FW - 1);            // 255
    const float inv_cm1 = 1.0f / (float)(CROP - 1);

    // ---- x math: shared by all 4 rows -----------------------------------
    const float xs = fmaf((float)j, (x2 - x1) * wm1 * inv_cm1, x1 * wm1);
    const bool xvalid = (xs >= 0.0f) && (xs <= wm1);
    const float x0f = floorf(xs);
    const float lx = xs - x0f;
    const int x0  = min(max((int)x0f, 0), FW - 1);
    const int x1i = min(x0 + 1, FW - 1);
    const int xb0 = x0  * FC + c;                 // float-index within a feature row
    const int xb1 = x1i * FC + c;

    // ---- y math per row -------------------------------------------------
    const float ybase = y1 * hm1;
    const float ystep = (y2 - y1) * hm1 * inv_cm1;

    float ly[4];
    int   yb0[4], yb1[4];
    bool  valid[4];
#pragma unroll
    for (int r = 0; r < 4; ++r) {
        const float ys = fmaf((float)(i0 + r), ystep, ybase);
        valid[r] = xvalid && (ys >= 0.0f) && (ys <= hm1);
        const float y0f = floorf(ys);
        ly[r] = ys - y0f;
        const int y0 = min(max((int)y0f, 0), FH - 1);
        const int y1c = min(y0 + 1, FH - 1);
        yb0[r] = y0  * (FW * FC);
        yb1[r] = y1c * (FW * FC);
    }

    const float* base = feats + (size_t)b * (FH * FW * FC);

    // ---- issue all 16 loads upfront for maximum MLP ---------------------
    f32x4 v00[4], v01[4], v10[4], v11[4];
#pragma unroll
    for (int r = 0; r < 4; ++r) {
        v00[r] = *reinterpret_cast<const f32x4*>(base + yb0[r] + xb0);
        v01[r] = *reinterpret_cast<const f32x4*>(base + yb0[r] + xb1);
        v10[r] = *reinterpret_cast<const f32x4*>(base + yb1[r] + xb0);
        v11[r] = *reinterpret_cast<const f32x4*>(base + yb1[r] + xb1);
    }

    // ---- lerp + plain store per row -------------------------------------
    const size_t pos0 = (size_t)rIdx * (CROP * CROP) + (size_t)i0 * CROP + j;
    float* outp = out + pos0 * FC + c;

#pragma unroll
    for (int r = 0; r < 4; ++r) {
        f32x4 res = lerp2d(v00[r], v01[r], v10[r], v11[r], lx, ly[r]);
        if (!valid[r]) { res = (f32x4)(0.0f); }
        *reinterpret_cast<f32x4*>(outp + (size_t)r * (CROP * FC)) = res;
    }
}

extern "C" void kernel_launch(void* const* d_in, const int* in_sizes, int n_in,
                              void* d_out, int out_size, void* d_ws, size_t ws_size,
                              hipStream_t stream) {
    const float* feats = (const float*)d_in[0];
    const float* rois  = (const float*)d_in[1];
    float* out = (float*)d_out;

    const int total_groups = 4 * 64 * CROP * (CROP / 4);  // 200704 (j, 4-row groups)
    const int total_threads = total_groups * 16;          // 3211264
    const int block = 256;
    const int grid = total_threads / block;               // 12544 (exact)

    roialign_kernel<<<grid, block, 0, stream>>>(feats, rois, out);
}